// Round 1
// baseline (500.013 us; speedup 1.0000x reference)
//
#include <hip/hip_runtime.h>
#include <float.h>

// Problem constants (from reference): N=8192 nodes, F_IN=F_OUT=128.
constexpr int N = 8192;
constexpr int F = 128;
constexpr int CAP = 1024;  // max neighbors/row we store; Binomial(8192,0.01) max ~130, 1024 is untouchable headroom

// ---------------------------------------------------------------------------
// Kernel 1: h = x @ W   (8192x128 @ 128x128, fp32 vector ALU)
// 128 threads/block (thread = output feature f), 8 rows per block.
// ---------------------------------------------------------------------------
__global__ __launch_bounds__(128) void gemm_xw(const float* __restrict__ x,
                                               const float* __restrict__ w,
                                               float* __restrict__ h) {
    __shared__ float xs[8][F];
    const int f = threadIdx.x;          // 0..127
    const int row0 = blockIdx.x * 8;

    #pragma unroll
    for (int r = 0; r < 8; ++r) xs[r][f] = x[(size_t)(row0 + r) * F + f];
    __syncthreads();

    float acc[8];
    #pragma unroll
    for (int r = 0; r < 8; ++r) acc[r] = 0.f;

    for (int k = 0; k < F; ++k) {
        const float wk = w[(size_t)k * F + f];   // coalesced across lanes, L1-resident
        #pragma unroll
        for (int r = 0; r < 8; ++r) acc[r] += xs[r][k] * wk;
    }

    #pragma unroll
    for (int r = 0; r < 8; ++r) h[(size_t)(row0 + r) * F + f] = acc[r];
}

// ---------------------------------------------------------------------------
// Kernel 2: out2 = relu(adj @ h + bias)
// One block per row. Phase 1: compact nonzero col indices of adj[row,:] into
// LDS (float4 streaming read of the 32 KB row). Phase 2: 2 waves x 128 lanes,
// lane = feature, halves split the neighbor list, sum h[j][f], combine, bias,
// relu, store.
// ---------------------------------------------------------------------------
__global__ __launch_bounds__(256) void aggregate_relu(const float* __restrict__ adj,
                                                      const float* __restrict__ h,
                                                      const float* __restrict__ bias,
                                                      float* __restrict__ out2) {
    __shared__ int idx[CAP];
    __shared__ int cnt;
    __shared__ float partial[F];

    const int tid = threadIdx.x;
    const int row = blockIdx.x;

    if (tid == 0) cnt = 0;
    __syncthreads();

    const float4* arow = (const float4*)(adj + (size_t)row * N);
    #pragma unroll
    for (int it = 0; it < N / 4 / 256; ++it) {   // 8 iterations
        const int j4 = tid + it * 256;
        const float4 v = arow[j4];
        if (v.x != 0.f) { int s = atomicAdd(&cnt, 1); if (s < CAP) idx[s] = 4 * j4 + 0; }
        if (v.y != 0.f) { int s = atomicAdd(&cnt, 1); if (s < CAP) idx[s] = 4 * j4 + 1; }
        if (v.z != 0.f) { int s = atomicAdd(&cnt, 1); if (s < CAP) idx[s] = 4 * j4 + 2; }
        if (v.w != 0.f) { int s = atomicAdd(&cnt, 1); if (s < CAP) idx[s] = 4 * j4 + 3; }
    }
    __syncthreads();

    const int n = min(cnt, CAP);
    const int f = tid & (F - 1);
    const int half = tid >> 7;          // 0 or 1

    float acc = 0.f;
    for (int e = half; e < n; e += 2) {
        acc += h[(size_t)idx[e] * F + f];
    }

    if (half == 1) partial[f] = acc;
    __syncthreads();
    if (half == 0) {
        acc += partial[f];
        const float v = acc + bias[f];
        out2[(size_t)row * F + f] = v > 0.f ? v : 0.f;
    }
}

// ---------------------------------------------------------------------------
// Kernel 3: out[i][f] = max over j with adj[i][j]!=0 of out2[j][f]
// Same structure as kernel 2 with max-accumulate. Self-loops guarantee n>=1.
// ---------------------------------------------------------------------------
__global__ __launch_bounds__(256) void neighbor_max(const float* __restrict__ adj,
                                                    const float* __restrict__ out2,
                                                    float* __restrict__ out) {
    __shared__ int idx[CAP];
    __shared__ int cnt;
    __shared__ float partial[F];

    const int tid = threadIdx.x;
    const int row = blockIdx.x;

    if (tid == 0) cnt = 0;
    __syncthreads();

    const float4* arow = (const float4*)(adj + (size_t)row * N);
    #pragma unroll
    for (int it = 0; it < N / 4 / 256; ++it) {
        const int j4 = tid + it * 256;
        const float4 v = arow[j4];
        if (v.x != 0.f) { int s = atomicAdd(&cnt, 1); if (s < CAP) idx[s] = 4 * j4 + 0; }
        if (v.y != 0.f) { int s = atomicAdd(&cnt, 1); if (s < CAP) idx[s] = 4 * j4 + 1; }
        if (v.z != 0.f) { int s = atomicAdd(&cnt, 1); if (s < CAP) idx[s] = 4 * j4 + 2; }
        if (v.w != 0.f) { int s = atomicAdd(&cnt, 1); if (s < CAP) idx[s] = 4 * j4 + 3; }
    }
    __syncthreads();

    const int n = min(cnt, CAP);
    const int f = tid & (F - 1);
    const int half = tid >> 7;

    float acc = -FLT_MAX;
    for (int e = half; e < n; e += 2) {
        acc = fmaxf(acc, out2[(size_t)idx[e] * F + f]);
    }

    if (half == 1) partial[f] = acc;
    __syncthreads();
    if (half == 0) {
        acc = fmaxf(acc, partial[f]);
        out[(size_t)row * F + f] = acc;
    }
}

// ---------------------------------------------------------------------------
// Host launcher. Inputs (setup_inputs order): x[N*F], adj[N*N], weight[F*F],
// bias[F]. Output: fp32 [N*F]. Workspace: h (4 MB) + out2 (4 MB) = 8 MB.
// ---------------------------------------------------------------------------
extern "C" void kernel_launch(void* const* d_in, const int* in_sizes, int n_in,
                              void* d_out, int out_size, void* d_ws, size_t ws_size,
                              hipStream_t stream) {
    const float* x    = (const float*)d_in[0];
    const float* adj  = (const float*)d_in[1];
    const float* w    = (const float*)d_in[2];
    const float* bias = (const float*)d_in[3];
    float* out = (float*)d_out;

    float* h    = (float*)d_ws;                  // [N, F]
    float* out2 = h + (size_t)N * F;             // [N, F]

    gemm_xw<<<N / 8, 128, 0, stream>>>(x, w, h);
    aggregate_relu<<<N, 256, 0, stream>>>(adj, h, bias, out2);
    neighbor_max<<<N, 256, 0, stream>>>(adj, out2, out);
}

// Round 2
// 460.637 us; speedup vs baseline: 1.0855x; 1.0855x over previous
//
#include <hip/hip_runtime.h>
#include <float.h>

// Problem constants: N=8192 nodes, F_IN=F_OUT=128, adj ~1% dense + self-loops.
constexpr int N = 8192;
constexpr int F = 128;
// Max neighbors/row stored. Degree ~ Binomial(8192, 0.01)+1: mean 82.9, std 9.
// 256 is >18 sigma headroom — unreachable.
constexpr int CAP = 256;

// ---------------------------------------------------------------------------
// Kernel 1: h = x @ W   (8192x128 @ 128x128, fp32 vector ALU — no fp32 MFMA)
// ---------------------------------------------------------------------------
__global__ __launch_bounds__(128) void gemm_xw(const float* __restrict__ x,
                                               const float* __restrict__ w,
                                               float* __restrict__ h) {
    __shared__ float xs[8][F];
    const int f = threadIdx.x;          // 0..127
    const int row0 = blockIdx.x * 8;

    #pragma unroll
    for (int r = 0; r < 8; ++r) xs[r][f] = x[(size_t)(row0 + r) * F + f];
    __syncthreads();

    float acc[8];
    #pragma unroll
    for (int r = 0; r < 8; ++r) acc[r] = 0.f;

    for (int k = 0; k < F; ++k) {
        const float wk = w[(size_t)k * F + f];   // coalesced, L1-resident
        #pragma unroll
        for (int r = 0; r < 8; ++r) acc[r] += xs[r][k] * wk;
    }

    #pragma unroll
    for (int r = 0; r < 8; ++r) h[(size_t)(row0 + r) * F + f] = acc[r];
}

// ---------------------------------------------------------------------------
// Kernel 2: scan adj row -> compact neighbor list (LDS) -> CSR to d_ws
//           AND out2 = relu(sum_j h[j] + bias).
// One block / row; 256 threads. This is the ONLY kernel reading adj (256 MB).
// ---------------------------------------------------------------------------
__global__ __launch_bounds__(256) void aggregate_relu_build_csr(
        const float* __restrict__ adj,
        const float* __restrict__ h,
        const float* __restrict__ bias,
        float* __restrict__ out2,
        unsigned short* __restrict__ csr_idx,   // [N, CAP]
        int* __restrict__ csr_cnt) {            // [N]
    __shared__ int idx[CAP];
    __shared__ int cnt;
    __shared__ float partial[F];

    const int tid = threadIdx.x;
    const int row = blockIdx.x;

    if (tid == 0) cnt = 0;
    __syncthreads();

    // Phase 1: streaming float4 scan of the 32 KB adjacency row.
    const float4* arow = (const float4*)(adj + (size_t)row * N);
    #pragma unroll
    for (int it = 0; it < N / 4 / 256; ++it) {   // 8 iterations
        const int j4 = tid + it * 256;
        const float4 v = arow[j4];
        if (v.x != 0.f) { int s = atomicAdd(&cnt, 1); if (s < CAP) idx[s] = 4 * j4 + 0; }
        if (v.y != 0.f) { int s = atomicAdd(&cnt, 1); if (s < CAP) idx[s] = 4 * j4 + 1; }
        if (v.z != 0.f) { int s = atomicAdd(&cnt, 1); if (s < CAP) idx[s] = 4 * j4 + 2; }
        if (v.w != 0.f) { int s = atomicAdd(&cnt, 1); if (s < CAP) idx[s] = 4 * j4 + 3; }
    }
    __syncthreads();

    const int n = min(cnt, CAP);

    // Mirror the list to global CSR for kernel 3 (n <= 256 == blockDim).
    if (tid == 0) csr_cnt[row] = n;
    if (tid < n) csr_idx[(size_t)row * CAP + tid] = (unsigned short)idx[tid];

    // Phase 2: sum-gather h rows. lane = feature, two halves split the list.
    const int f = tid & (F - 1);
    const int half = tid >> 7;          // 0 or 1

    float acc = 0.f;
    for (int e = half; e < n; e += 2) {
        acc += h[(size_t)idx[e] * F + f];
    }

    if (half == 1) partial[f] = acc;
    __syncthreads();
    if (half == 0) {
        acc += partial[f];
        const float v = acc + bias[f];
        out2[(size_t)row * F + f] = v > 0.f ? v : 0.f;
    }
}

// ---------------------------------------------------------------------------
// Kernel 3: out[i][f] = max_{j in csr[i]} out2[j][f].  CSR only — no adj read.
// out2 is 4 MB -> L2/L3 resident; this kernel is gather-latency bound.
// ---------------------------------------------------------------------------
__global__ __launch_bounds__(256) void neighbor_max_csr(
        const unsigned short* __restrict__ csr_idx,
        const int* __restrict__ csr_cnt,
        const float* __restrict__ out2,
        float* __restrict__ out) {
    __shared__ int idx[CAP];
    __shared__ float partial[F];

    const int tid = threadIdx.x;
    const int row = blockIdx.x;

    const int n = csr_cnt[row];
    if (tid < n) idx[tid] = csr_idx[(size_t)row * CAP + tid];
    __syncthreads();

    const int f = tid & (F - 1);
    const int half = tid >> 7;

    float acc = -FLT_MAX;
    for (int e = half; e < n; e += 2) {
        acc = fmaxf(acc, out2[(size_t)idx[e] * F + f]);
    }

    if (half == 1) partial[f] = acc;
    __syncthreads();
    if (half == 0) {
        acc = fmaxf(acc, partial[f]);   // self-loop guarantees n >= 1
        out[(size_t)row * F + f] = acc;
    }
}

// ---------------------------------------------------------------------------
// Host launcher. Inputs: x[N*F], adj[N*N], weight[F*F], bias[F].
// Output: fp32 [N*F]. Workspace: h(4MB) + out2(4MB) + csr_cnt(32KB) +
// csr_idx(4MB uint16) = ~12 MB.
// ---------------------------------------------------------------------------
extern "C" void kernel_launch(void* const* d_in, const int* in_sizes, int n_in,
                              void* d_out, int out_size, void* d_ws, size_t ws_size,
                              hipStream_t stream) {
    const float* x    = (const float*)d_in[0];
    const float* adj  = (const float*)d_in[1];
    const float* w    = (const float*)d_in[2];
    const float* bias = (const float*)d_in[3];
    float* out = (float*)d_out;

    float* h    = (float*)d_ws;                           // [N, F]
    float* out2 = h + (size_t)N * F;                      // [N, F]
    int* csr_cnt = (int*)(out2 + (size_t)N * F);          // [N]
    unsigned short* csr_idx = (unsigned short*)(csr_cnt + N);  // [N, CAP]

    gemm_xw<<<N / 8, 128, 0, stream>>>(x, w, h);
    aggregate_relu_build_csr<<<N, 256, 0, stream>>>(adj, h, bias, out2, csr_idx, csr_cnt);
    neighbor_max_csr<<<N, 256, 0, stream>>>(csr_idx, csr_cnt, out2, out);
}

// Round 3
// 401.719 us; speedup vs baseline: 1.2447x; 1.1467x over previous
//
#include <hip/hip_runtime.h>
#include <float.h>

// Problem constants: N=8192 nodes, F_IN=F_OUT=128, adj ~1% dense + self-loops.
constexpr int N = 8192;
constexpr int F = 128;
// Max neighbors/row. Degree ~ Binomial(8191,0.01)+1: mean 82.9, sigma 9.
// 256 is ~19 sigma headroom — statistically unreachable.
constexpr int CAP = 256;

// ---------------------------------------------------------------------------
// Kernel 1: h = x @ W   (8192x128 @ 128x128, fp32 vector ALU — no fp32 MFMA)
// ---------------------------------------------------------------------------
__global__ __launch_bounds__(128) void gemm_xw(const float* __restrict__ x,
                                               const float* __restrict__ w,
                                               float* __restrict__ h) {
    __shared__ float xs[8][F];
    const int f = threadIdx.x;          // 0..127
    const int row0 = blockIdx.x * 8;

    #pragma unroll
    for (int r = 0; r < 8; ++r) xs[r][f] = x[(size_t)(row0 + r) * F + f];
    __syncthreads();

    float acc[8];
    #pragma unroll
    for (int r = 0; r < 8; ++r) acc[r] = 0.f;

    for (int k = 0; k < F; ++k) {
        const float wk = w[(size_t)k * F + f];   // coalesced, L1-resident
        #pragma unroll
        for (int r = 0; r < 8; ++r) acc[r] += xs[r][k] * wk;
    }

    #pragma unroll
    for (int r = 0; r < 8; ++r) h[(size_t)(row0 + r) * F + f] = acc[r];
}

// ---------------------------------------------------------------------------
// Kernel 2: scan adj row (all loads issued up front -> BW-bound), ballot-based
// compaction (1 LDS atomic per wave-iter), CSR mirror to d_ws, then
// out2 = relu(sum_j h[j] + bias). One block / row; 256 threads (4 waves).
// This is the ONLY kernel reading adj (256 MB) — the session's traffic floor.
// ---------------------------------------------------------------------------
__global__ __launch_bounds__(256) void aggregate_relu_build_csr(
        const float* __restrict__ adj,
        const float* __restrict__ h,
        const float* __restrict__ bias,
        float* __restrict__ out2,
        unsigned short* __restrict__ csr_idx,   // [N, CAP]
        int* __restrict__ csr_cnt) {            // [N]
    __shared__ int idx[CAP];
    __shared__ int cnt;
    __shared__ float partial[F];

    const int tid  = threadIdx.x;
    const int lane = tid & 63;
    const int row  = blockIdx.x;

    if (tid == 0) cnt = 0;
    __syncthreads();

    // ---- Phase 1a: issue ALL 8 float4 loads for this block's 32 KB row. ----
    const float4* arow = (const float4*)(adj + (size_t)row * N);
    float4 v[8];
    #pragma unroll
    for (int it = 0; it < 8; ++it) v[it] = arow[tid + it * 256];

    // ---- Phase 1b: wave-ballot compaction (order-insensitive). ----
    const unsigned long long lt = (1ull << lane) - 1ull;
    #pragma unroll
    for (int it = 0; it < 8; ++it) {
        const int j4 = 4 * (tid + it * 256);   // global col of component .x
        const float4 vv = v[it];
        const unsigned long long m0 = __ballot(vv.x != 0.f);
        const unsigned long long m1 = __ballot(vv.y != 0.f);
        const unsigned long long m2 = __ballot(vv.z != 0.f);
        const unsigned long long m3 = __ballot(vv.w != 0.f);
        const int c0 = __popcll(m0), c1 = __popcll(m1),
                  c2 = __popcll(m2), c3 = __popcll(m3);
        const int tot = c0 + c1 + c2 + c3;
        int base = 0;
        if (lane == 0 && tot) base = atomicAdd(&cnt, tot);
        base = __shfl(base, 0, 64);
        if (vv.x != 0.f) idx[base + __popcll(m0 & lt)] = j4 + 0;
        base += c0;
        if (vv.y != 0.f) idx[base + __popcll(m1 & lt)] = j4 + 1;
        base += c1;
        if (vv.z != 0.f) idx[base + __popcll(m2 & lt)] = j4 + 2;
        base += c2;
        if (vv.w != 0.f) idx[base + __popcll(m3 & lt)] = j4 + 3;
    }
    __syncthreads();

    const int n = min(cnt, CAP);

    // Mirror the list to global CSR for kernel 3 (n <= 256 == blockDim).
    if (tid == 0) csr_cnt[row] = n;
    if (tid < n) csr_idx[(size_t)row * CAP + tid] = (unsigned short)idx[tid];

    // ---- Phase 2: sum-gather h rows. lane = feature, 2 halves split the ----
    // ---- list; 4x unroll keeps 4 gathers in flight per lane.            ----
    const int f = tid & (F - 1);
    const int half = tid >> 7;          // 0 or 1

    float acc = 0.f;
    int e = half;
    for (; e + 6 < n; e += 8) {
        const int j0 = idx[e], j1 = idx[e + 2], j2 = idx[e + 4], j3 = idx[e + 6];
        const float a0 = h[(size_t)j0 * F + f];
        const float a1 = h[(size_t)j1 * F + f];
        const float a2 = h[(size_t)j2 * F + f];
        const float a3 = h[(size_t)j3 * F + f];
        acc += (a0 + a1) + (a2 + a3);
    }
    for (; e < n; e += 2) acc += h[(size_t)idx[e] * F + f];

    if (half == 1) partial[f] = acc;
    __syncthreads();
    if (half == 0) {
        acc += partial[f];
        const float vb = acc + bias[f];
        out2[(size_t)row * F + f] = vb > 0.f ? vb : 0.f;
    }
}

// ---------------------------------------------------------------------------
// Kernel 3: out[i][f] = max_{j in csr[i]} out2[j][f].  CSR only — no adj read.
// out2 is 4 MB -> L2-resident; gather-latency bound, 4x unrolled.
// ---------------------------------------------------------------------------
__global__ __launch_bounds__(256) void neighbor_max_csr(
        const unsigned short* __restrict__ csr_idx,
        const int* __restrict__ csr_cnt,
        const float* __restrict__ out2,
        float* __restrict__ out) {
    __shared__ int idx[CAP];
    __shared__ float partial[F];

    const int tid = threadIdx.x;
    const int row = blockIdx.x;

    const int n = csr_cnt[row];
    if (tid < n) idx[tid] = csr_idx[(size_t)row * CAP + tid];
    __syncthreads();

    const int f = tid & (F - 1);
    const int half = tid >> 7;

    float acc = -FLT_MAX;
    int e = half;
    for (; e + 6 < n; e += 8) {
        const int j0 = idx[e], j1 = idx[e + 2], j2 = idx[e + 4], j3 = idx[e + 6];
        const float a0 = out2[(size_t)j0 * F + f];
        const float a1 = out2[(size_t)j1 * F + f];
        const float a2 = out2[(size_t)j2 * F + f];
        const float a3 = out2[(size_t)j3 * F + f];
        acc = fmaxf(acc, fmaxf(fmaxf(a0, a1), fmaxf(a2, a3)));
    }
    for (; e < n; e += 2) acc = fmaxf(acc, out2[(size_t)idx[e] * F + f]);

    if (half == 1) partial[f] = acc;
    __syncthreads();
    if (half == 0) {
        acc = fmaxf(acc, partial[f]);   // self-loop guarantees n >= 1
        out[(size_t)row * F + f] = acc;
    }
}

// ---------------------------------------------------------------------------
// Host launcher. Inputs: x[N*F], adj[N*N], weight[F*F], bias[F].
// Output: fp32 [N*F]. Workspace: h(4MB) + out2(4MB) + csr_cnt(32KB) +
// csr_idx(4MB uint16) = ~12 MB.
// ---------------------------------------------------------------------------
extern "C" void kernel_launch(void* const* d_in, const int* in_sizes, int n_in,
                              void* d_out, int out_size, void* d_ws, size_t ws_size,
                              hipStream_t stream) {
    const float* x    = (const float*)d_in[0];
    const float* adj  = (const float*)d_in[1];
    const float* w    = (const float*)d_in[2];
    const float* bias = (const float*)d_in[3];
    float* out = (float*)d_out;

    float* h    = (float*)d_ws;                           // [N, F]
    float* out2 = h + (size_t)N * F;                      // [N, F]
    int* csr_cnt = (int*)(out2 + (size_t)N * F);          // [N]
    unsigned short* csr_idx = (unsigned short*)(csr_cnt + N);  // [N, CAP]

    gemm_xw<<<N / 8, 128, 0, stream>>>(x, w, h);
    aggregate_relu_build_csr<<<N, 256, 0, stream>>>(adj, h, bias, out2, csr_idx, csr_cnt);
    neighbor_max_csr<<<N, 256, 0, stream>>>(csr_idx, csr_cnt, out2, out);
}

// Round 5
// 386.460 us; speedup vs baseline: 1.2938x; 1.0395x over previous
//
#include <hip/hip_runtime.h>
#include <float.h>

// Problem constants: N=8192 nodes, F_IN=F_OUT=128, adj ~1% dense + self-loops.
constexpr int N = 8192;
constexpr int F = 128;
// Max neighbors/row. Degree ~ Binomial(8191,0.01)+1: mean 82.9, sigma 9.
// 256 is ~19 sigma headroom — statistically unreachable.
constexpr int CAP = 256;

using short8 = __attribute__((ext_vector_type(8))) short;   // 8 bf16 = 4 VGPRs
using float4v = __attribute__((ext_vector_type(4))) float;  // MFMA C/D & NT loads

static __device__ inline unsigned short f2bf(float f) {
    unsigned u = __float_as_uint(f);
    u += 0x7fffu + ((u >> 16) & 1u);    // RNE
    return (unsigned short)(u >> 16);
}
static __device__ inline float bf2f(unsigned short s) {
    return __uint_as_float((unsigned)s << 16);
}

// ---------------------------------------------------------------------------
// Kernel 1: h = x @ W, bf16 MFMA (16x16x32), h stored as bf16.
// 128 blocks x 256 thr (4 waves). Block = 64 rows x 128 cols; wave = 16 rows.
// A layout: A[m=lane&15][k=quad*8+j]; B[k=quad*8+j][n=lane&15];
// C/D: col=lane&15, row=quad*4+reg  (verified layouts, learn_hip m89/m91/m120)
// ---------------------------------------------------------------------------
constexpr int KP = 136;   // padded K stride (x2B = 272 B: 16B-aligned rows)

__global__ __launch_bounds__(256) void gemm_mfma(const float* __restrict__ x,
                                                 const float* __restrict__ w,
                                                 unsigned short* __restrict__ h) {
    __shared__ unsigned short xs[64][KP];   // bf16 x-tile   (17.4 KB)
    __shared__ unsigned short wt[128][KP];  // bf16 W^T      (34.8 KB)

    const int tid = threadIdx.x;
    const int row0 = blockIdx.x * 64;

    // Stage x tile (64x128 fp32 -> bf16).  2048 float4 / 256 thr = 8 each.
    {
        const float4* x4 = (const float4*)(x + (size_t)row0 * F);
        #pragma unroll
        for (int i = tid; i < 64 * F / 4; i += 256) {
            const float4 v = x4[i];
            const int r = (i * 4) >> 7, c = (i * 4) & 127;
            xs[r][c + 0] = f2bf(v.x); xs[r][c + 1] = f2bf(v.y);
            xs[r][c + 2] = f2bf(v.z); xs[r][c + 3] = f2bf(v.w);
        }
    }
    // Stage W^T (128x128 fp32 -> bf16 transposed).  4096 float4 / 256 = 16 each.
    {
        const float4* w4 = (const float4*)w;
        #pragma unroll
        for (int i = tid; i < F * F / 4; i += 256) {
            const float4 v = w4[i];
            const int k = (i * 4) >> 7, n = (i * 4) & 127;
            wt[n + 0][k] = f2bf(v.x); wt[n + 1][k] = f2bf(v.y);
            wt[n + 2][k] = f2bf(v.z); wt[n + 3][k] = f2bf(v.w);
        }
    }
    __syncthreads();

    const int lane = tid & 63, wid = tid >> 6;
    const int m = lane & 15, quad = lane >> 4;
    const int m0 = wid * 16;

    float4v acc[8];
    #pragma unroll
    for (int nt = 0; nt < 8; ++nt) acc[nt] = (float4v){0.f, 0.f, 0.f, 0.f};

    #pragma unroll
    for (int k0 = 0; k0 < F; k0 += 32) {
        const short8 a = *(const short8*)&xs[m0 + m][k0 + quad * 8];
        #pragma unroll
        for (int nt = 0; nt < 8; ++nt) {
            const short8 b = *(const short8*)&wt[nt * 16 + m][k0 + quad * 8];
            acc[nt] = __builtin_amdgcn_mfma_f32_16x16x32_bf16(a, b, acc[nt], 0, 0, 0);
        }
    }

    #pragma unroll
    for (int nt = 0; nt < 8; ++nt)
        #pragma unroll
        for (int r = 0; r < 4; ++r) {
            const int row = row0 + m0 + quad * 4 + r;
            const int col = nt * 16 + m;
            h[(size_t)row * F + col] = f2bf(acc[nt][r]);
        }
}

// ---------------------------------------------------------------------------
// Kernel 2: scan adj row (nontemporal float4, all loads in flight), ballot
// compaction (1 LDS atomic / wave-iter), CSR mirror, then
// out2 = relu(sum_j h_bf16[j] + bias) stored as bf16.
// Only kernel reading adj (256 MB) — the session's HBM floor.
// ---------------------------------------------------------------------------
__global__ __launch_bounds__(256) void aggregate_relu_build_csr(
        const float* __restrict__ adj,
        const unsigned short* __restrict__ h,
        const float* __restrict__ bias,
        unsigned short* __restrict__ out2,
        unsigned short* __restrict__ csr_idx,   // [N, CAP]
        int* __restrict__ csr_cnt) {            // [N]
    __shared__ int idx[CAP];
    __shared__ int cnt;
    __shared__ float partial[F];

    const int tid  = threadIdx.x;
    const int lane = tid & 63;
    const int row  = blockIdx.x;

    if (tid == 0) cnt = 0;
    __syncthreads();

    // Phase 1a: all 8 nontemporal float4 loads of the 32 KB row in flight.
    // (native ext_vector_type — __builtin_nontemporal_load rejects HIP float4)
    const float4v* arow = (const float4v*)(adj + (size_t)row * N);
    float4v v[8];
    #pragma unroll
    for (int it = 0; it < 8; ++it) v[it] = __builtin_nontemporal_load(arow + tid + it * 256);

    // Phase 1b: wave-ballot compaction (order-insensitive: sum/max commute).
    const unsigned long long lt = (1ull << lane) - 1ull;
    #pragma unroll
    for (int it = 0; it < 8; ++it) {
        const int j4 = 4 * (tid + it * 256);
        const float4v vv = v[it];
        const unsigned long long m0 = __ballot(vv.x != 0.f);
        const unsigned long long m1 = __ballot(vv.y != 0.f);
        const unsigned long long m2 = __ballot(vv.z != 0.f);
        const unsigned long long m3 = __ballot(vv.w != 0.f);
        const int c0 = __popcll(m0), c1 = __popcll(m1),
                  c2 = __popcll(m2), c3 = __popcll(m3);
        const int tot = c0 + c1 + c2 + c3;
        int base = 0;
        if (lane == 0 && tot) base = atomicAdd(&cnt, tot);
        base = __shfl(base, 0, 64);
        if (vv.x != 0.f) idx[base + __popcll(m0 & lt)] = j4 + 0;
        base += c0;
        if (vv.y != 0.f) idx[base + __popcll(m1 & lt)] = j4 + 1;
        base += c1;
        if (vv.z != 0.f) idx[base + __popcll(m2 & lt)] = j4 + 2;
        base += c2;
        if (vv.w != 0.f) idx[base + __popcll(m3 & lt)] = j4 + 3;
    }
    __syncthreads();

    const int n = min(cnt, CAP);

    if (tid == 0) csr_cnt[row] = n;
    if (tid < n) csr_idx[(size_t)row * CAP + tid] = (unsigned short)idx[tid];

    // Phase 2: sum-gather bf16 h rows. lane = feature; halves split the list.
    const int f = tid & (F - 1);
    const int half = tid >> 7;

    float acc = 0.f;
    int e = half;
    for (; e + 6 < n; e += 8) {
        const int j0 = idx[e], j1 = idx[e + 2], j2 = idx[e + 4], j3 = idx[e + 6];
        const float a0 = bf2f(h[(size_t)j0 * F + f]);
        const float a1 = bf2f(h[(size_t)j1 * F + f]);
        const float a2 = bf2f(h[(size_t)j2 * F + f]);
        const float a3 = bf2f(h[(size_t)j3 * F + f]);
        acc += (a0 + a1) + (a2 + a3);
    }
    for (; e < n; e += 2) acc += bf2f(h[(size_t)idx[e] * F + f]);

    if (half == 1) partial[f] = acc;
    __syncthreads();
    if (half == 0) {
        acc += partial[f];
        const float vb = acc + bias[f];
        out2[(size_t)row * F + f] = f2bf(vb > 0.f ? vb : 0.f);
    }
}

// ---------------------------------------------------------------------------
// Kernel 3: out[i][f] = max_{j in csr[i]} out2[j][f].  CSR + bf16 out2 (2 MB,
// L2-resident). Final output fp32.
// ---------------------------------------------------------------------------
__global__ __launch_bounds__(256) void neighbor_max_csr(
        const unsigned short* __restrict__ csr_idx,
        const int* __restrict__ csr_cnt,
        const unsigned short* __restrict__ out2,
        float* __restrict__ out) {
    __shared__ int idx[CAP];
    __shared__ float partial[F];

    const int tid = threadIdx.x;
    const int row = blockIdx.x;

    const int n = csr_cnt[row];
    if (tid < n) idx[tid] = csr_idx[(size_t)row * CAP + tid];
    __syncthreads();

    const int f = tid & (F - 1);
    const int half = tid >> 7;

    float acc = -FLT_MAX;
    int e = half;
    for (; e + 6 < n; e += 8) {
        const int j0 = idx[e], j1 = idx[e + 2], j2 = idx[e + 4], j3 = idx[e + 6];
        const float a0 = bf2f(out2[(size_t)j0 * F + f]);
        const float a1 = bf2f(out2[(size_t)j1 * F + f]);
        const float a2 = bf2f(out2[(size_t)j2 * F + f]);
        const float a3 = bf2f(out2[(size_t)j3 * F + f]);
        acc = fmaxf(acc, fmaxf(fmaxf(a0, a1), fmaxf(a2, a3)));
    }
    for (; e < n; e += 2) acc = fmaxf(acc, bf2f(out2[(size_t)idx[e] * F + f]));

    if (half == 1) partial[f] = acc;
    __syncthreads();
    if (half == 0) {
        acc = fmaxf(acc, partial[f]);   // self-loop guarantees n >= 1
        out[(size_t)row * F + f] = acc;
    }
}

// ---------------------------------------------------------------------------
// Host launcher. Inputs: x[N*F], adj[N*N], weight[F*F], bias[F].
// Output: fp32 [N*F]. Workspace: h(2MB bf16) + out2(2MB bf16) + csr_cnt(32KB)
// + csr_idx(4MB uint16) = ~8 MB.
// ---------------------------------------------------------------------------
extern "C" void kernel_launch(void* const* d_in, const int* in_sizes, int n_in,
                              void* d_out, int out_size, void* d_ws, size_t ws_size,
                              hipStream_t stream) {
    const float* x    = (const float*)d_in[0];
    const float* adj  = (const float*)d_in[1];
    const float* w    = (const float*)d_in[2];
    const float* bias = (const float*)d_in[3];
    float* out = (float*)d_out;

    unsigned short* h    = (unsigned short*)d_ws;              // [N, F] bf16
    unsigned short* out2 = h + (size_t)N * F;                  // [N, F] bf16
    int* csr_cnt = (int*)(out2 + (size_t)N * F);               // [N]
    unsigned short* csr_idx = (unsigned short*)(csr_cnt + N);  // [N, CAP]

    gemm_mfma<<<N / 64, 256, 0, stream>>>(x, w, h);
    aggregate_relu_build_csr<<<N, 256, 0, stream>>>(adj, h, bias, out2, csr_idx, csr_cnt);
    neighbor_max_csr<<<N, 256, 0, stream>>>(csr_idx, csr_cnt, out2, out);
}

// Round 6
// 374.572 us; speedup vs baseline: 1.3349x; 1.0317x over previous
//
#include <hip/hip_runtime.h>
#include <float.h>

// Problem constants: N=8192 nodes, F_IN=F_OUT=128, adj ~1% dense + self-loops.
constexpr int N = 8192;
constexpr int F = 128;
// Max neighbors/row. Degree ~ Binomial(8191,0.01)+1: mean 82.9, sigma 9.
// 256 is ~19 sigma headroom — statistically unreachable.
constexpr int CAP = 256;

using short8 = __attribute__((ext_vector_type(8))) short;   // 8 bf16 = 4 VGPRs
using float4v = __attribute__((ext_vector_type(4))) float;  // MFMA C/D & NT loads

static __device__ inline unsigned short f2bf(float f) {
    unsigned u = __float_as_uint(f);
    u += 0x7fffu + ((u >> 16) & 1u);    // RNE
    return (unsigned short)(u >> 16);
}
static __device__ inline float bf2f(unsigned short s) {
    return __uint_as_float((unsigned)s << 16);
}

// ---------------------------------------------------------------------------
// Kernel 1: h = x @ W, bf16 MFMA (16x16x32), h stored as bf16.
// 256 blocks x 256 thr (4 waves); block = 32 rows x 128 cols (full-chip grid;
// 128 blocks left half the CUs idle). Wave = 16 rows x 64 cols (4 n-tiles).
// A layout: A[m=lane&15][k=quad*8+j]; B[k=quad*8+j][n=lane&15];
// C/D: col=lane&15, row=quad*4+reg  (verified layouts, learn_hip m89/m91/m120)
// ---------------------------------------------------------------------------
constexpr int KP = 136;   // padded K stride (x2B = 272 B: 16B-aligned rows)

__global__ __launch_bounds__(256) void gemm_mfma(const float* __restrict__ x,
                                                 const float* __restrict__ w,
                                                 unsigned short* __restrict__ h) {
    __shared__ unsigned short xs[32][KP];   // bf16 x-tile   (8.7 KB)
    __shared__ unsigned short wt[128][KP];  // bf16 W^T      (34.8 KB)

    const int tid = threadIdx.x;
    const int row0 = blockIdx.x * 32;

    // Stage x tile (32x128 fp32 -> bf16).  1024 float4 / 256 thr = 4 each.
    {
        const float4* x4 = (const float4*)(x + (size_t)row0 * F);
        #pragma unroll
        for (int i = tid; i < 32 * F / 4; i += 256) {
            const float4 v = x4[i];
            const int r = (i * 4) >> 7, c = (i * 4) & 127;
            xs[r][c + 0] = f2bf(v.x); xs[r][c + 1] = f2bf(v.y);
            xs[r][c + 2] = f2bf(v.z); xs[r][c + 3] = f2bf(v.w);
        }
    }
    // Stage W^T (128x128 fp32 -> bf16 transposed).  4096 float4 / 256 = 16 each.
    // (bank conflicts here cost ~0.3 us total — measured irrelevant)
    {
        const float4* w4 = (const float4*)w;
        #pragma unroll
        for (int i = tid; i < F * F / 4; i += 256) {
            const float4 v = w4[i];
            const int k = (i * 4) >> 7, n = (i * 4) & 127;
            wt[n + 0][k] = f2bf(v.x); wt[n + 1][k] = f2bf(v.y);
            wt[n + 2][k] = f2bf(v.z); wt[n + 3][k] = f2bf(v.w);
        }
    }
    __syncthreads();

    const int lane = tid & 63, wid = tid >> 6;
    const int m = lane & 15, quad = lane >> 4;
    const int m0 = (wid & 1) * 16;      // row sub-tile
    const int nh = (wid >> 1) * 64;     // col half

    float4v acc[4];
    #pragma unroll
    for (int nt = 0; nt < 4; ++nt) acc[nt] = (float4v){0.f, 0.f, 0.f, 0.f};

    #pragma unroll
    for (int k0 = 0; k0 < F; k0 += 32) {
        const short8 a = *(const short8*)&xs[m0 + m][k0 + quad * 8];
        #pragma unroll
        for (int nt = 0; nt < 4; ++nt) {
            const short8 b = *(const short8*)&wt[nh + nt * 16 + m][k0 + quad * 8];
            acc[nt] = __builtin_amdgcn_mfma_f32_16x16x32_bf16(a, b, acc[nt], 0, 0, 0);
        }
    }

    #pragma unroll
    for (int nt = 0; nt < 4; ++nt)
        #pragma unroll
        for (int r = 0; r < 4; ++r) {
            const int row = row0 + m0 + quad * 4 + r;
            const int col = nh + nt * 16 + m;
            h[(size_t)row * F + col] = f2bf(acc[nt][r]);
        }
}

// ---------------------------------------------------------------------------
// Kernel 2: scan adj row (nontemporal float4, all loads in flight), ballot
// compaction (1 LDS atomic / wave-iter), CSR mirror, then
// out2 = relu(sum_j h_bf16[j] + bias) stored as bf16.
// Gather: lane covers 2 features (packed uint load), 4 waves split the list
// 4-way, 4x unrolled -> 4 coalesced 4B gathers in flight per lane.
// Only kernel reading adj (256 MB) — the session's HBM floor.
// ---------------------------------------------------------------------------
__global__ __launch_bounds__(256) void aggregate_relu_build_csr(
        const float* __restrict__ adj,
        const unsigned short* __restrict__ h,
        const float* __restrict__ bias,
        unsigned short* __restrict__ out2,
        unsigned short* __restrict__ csr_idx,   // [N, CAP]
        int* __restrict__ csr_cnt) {            // [N]
    __shared__ int idx[CAP];
    __shared__ int cnt;
    __shared__ float2 p2[3][64];

    const int tid  = threadIdx.x;
    const int lane = tid & 63;
    const int wv   = tid >> 6;
    const int row  = blockIdx.x;

    if (tid == 0) cnt = 0;
    __syncthreads();

    // Phase 1a: all 8 nontemporal float4 loads of the 32 KB row in flight.
    const float4v* arow = (const float4v*)(adj + (size_t)row * N);
    float4v v[8];
    #pragma unroll
    for (int it = 0; it < 8; ++it) v[it] = __builtin_nontemporal_load(arow + tid + it * 256);

    // Phase 1b: wave-ballot compaction (order-insensitive: sum/max commute).
    const unsigned long long lt = (1ull << lane) - 1ull;
    #pragma unroll
    for (int it = 0; it < 8; ++it) {
        const int j4 = 4 * (tid + it * 256);
        const float4v vv = v[it];
        const unsigned long long m0 = __ballot(vv.x != 0.f);
        const unsigned long long m1 = __ballot(vv.y != 0.f);
        const unsigned long long m2 = __ballot(vv.z != 0.f);
        const unsigned long long m3 = __ballot(vv.w != 0.f);
        const int c0 = __popcll(m0), c1 = __popcll(m1),
                  c2 = __popcll(m2), c3 = __popcll(m3);
        const int tot = c0 + c1 + c2 + c3;
        int base = 0;
        if (lane == 0 && tot) base = atomicAdd(&cnt, tot);
        base = __shfl(base, 0, 64);
        if (vv.x != 0.f) idx[base + __popcll(m0 & lt)] = j4 + 0;
        base += c0;
        if (vv.y != 0.f) idx[base + __popcll(m1 & lt)] = j4 + 1;
        base += c1;
        if (vv.z != 0.f) idx[base + __popcll(m2 & lt)] = j4 + 2;
        base += c2;
        if (vv.w != 0.f) idx[base + __popcll(m3 & lt)] = j4 + 3;
    }
    __syncthreads();

    const int n = min(cnt, CAP);

    if (tid == 0) csr_cnt[row] = n;
    if (tid < n) csr_idx[(size_t)row * CAP + tid] = (unsigned short)idx[tid];

    // Phase 2: sum-gather. h viewed as [N][64] packed bf16 pairs.
    const unsigned* h32 = (const unsigned*)h;
    float a0 = 0.f, a1 = 0.f;
    int e = wv;
    for (; e + 12 < n; e += 16) {
        const unsigned u0 = h32[(size_t)idx[e]      * 64 + lane];
        const unsigned u1 = h32[(size_t)idx[e + 4]  * 64 + lane];
        const unsigned u2 = h32[(size_t)idx[e + 8]  * 64 + lane];
        const unsigned u3 = h32[(size_t)idx[e + 12] * 64 + lane];
        a0 += (bf2f((unsigned short)u0) + bf2f((unsigned short)u1))
            + (bf2f((unsigned short)u2) + bf2f((unsigned short)u3));
        a1 += (bf2f((unsigned short)(u0 >> 16)) + bf2f((unsigned short)(u1 >> 16)))
            + (bf2f((unsigned short)(u2 >> 16)) + bf2f((unsigned short)(u3 >> 16)));
    }
    for (; e < n; e += 4) {
        const unsigned u = h32[(size_t)idx[e] * 64 + lane];
        a0 += bf2f((unsigned short)u);
        a1 += bf2f((unsigned short)(u >> 16));
    }

    if (wv) p2[wv - 1][lane] = make_float2(a0, a1);
    __syncthreads();
    if (wv == 0) {
        a0 += p2[0][lane].x + p2[1][lane].x + p2[2][lane].x;
        a1 += p2[0][lane].y + p2[1][lane].y + p2[2][lane].y;
        const float2 b2 = ((const float2*)bias)[lane];
        float v0 = a0 + b2.x, v1 = a1 + b2.y;
        v0 = v0 > 0.f ? v0 : 0.f;
        v1 = v1 > 0.f ? v1 : 0.f;
        ((unsigned*)out2)[(size_t)row * 64 + lane] =
            (unsigned)f2bf(v0) | ((unsigned)f2bf(v1) << 16);
    }
}

// ---------------------------------------------------------------------------
// Kernel 3: out[i][f] = max_{j in csr[i]} out2[j][f].  CSR + bf16 out2 (2 MB,
// L2-resident). Packed-pair gathers, 4-way list split. Output fp32.
// ---------------------------------------------------------------------------
__global__ __launch_bounds__(256) void neighbor_max_csr(
        const unsigned short* __restrict__ csr_idx,
        const int* __restrict__ csr_cnt,
        const unsigned short* __restrict__ out2,
        float* __restrict__ out) {
    __shared__ int idx[CAP];
    __shared__ float2 p2[3][64];

    const int tid  = threadIdx.x;
    const int lane = tid & 63;
    const int wv   = tid >> 6;
    const int row  = blockIdx.x;

    const int n = csr_cnt[row];
    if (tid < n) idx[tid] = csr_idx[(size_t)row * CAP + tid];
    __syncthreads();

    const unsigned* o32 = (const unsigned*)out2;
    float a0 = -FLT_MAX, a1 = -FLT_MAX;
    int e = wv;
    for (; e + 12 < n; e += 16) {
        const unsigned u0 = o32[(size_t)idx[e]      * 64 + lane];
        const unsigned u1 = o32[(size_t)idx[e + 4]  * 64 + lane];
        const unsigned u2 = o32[(size_t)idx[e + 8]  * 64 + lane];
        const unsigned u3 = o32[(size_t)idx[e + 12] * 64 + lane];
        a0 = fmaxf(a0, fmaxf(fmaxf(bf2f((unsigned short)u0), bf2f((unsigned short)u1)),
                             fmaxf(bf2f((unsigned short)u2), bf2f((unsigned short)u3))));
        a1 = fmaxf(a1, fmaxf(fmaxf(bf2f((unsigned short)(u0 >> 16)), bf2f((unsigned short)(u1 >> 16))),
                             fmaxf(bf2f((unsigned short)(u2 >> 16)), bf2f((unsigned short)(u3 >> 16)))));
    }
    for (; e < n; e += 4) {
        const unsigned u = o32[(size_t)idx[e] * 64 + lane];
        a0 = fmaxf(a0, bf2f((unsigned short)u));
        a1 = fmaxf(a1, bf2f((unsigned short)(u >> 16)));
    }

    if (wv) p2[wv - 1][lane] = make_float2(a0, a1);
    __syncthreads();
    if (wv == 0) {
        // wave 0 always iterates (n >= 1 via self-loop), so a0/a1 are valid.
        a0 = fmaxf(a0, fmaxf(fmaxf(p2[0][lane].x, p2[1][lane].x), p2[2][lane].x));
        a1 = fmaxf(a1, fmaxf(fmaxf(p2[0][lane].y, p2[1][lane].y), p2[2][lane].y));
        ((float2*)out)[(size_t)row * 64 + lane] = make_float2(a0, a1);
    }
}

// ---------------------------------------------------------------------------
// Host launcher. Inputs: x[N*F], adj[N*N], weight[F*F], bias[F].
// Output: fp32 [N*F]. Workspace: h(2MB bf16) + out2(2MB bf16) + csr_cnt(32KB)
// + csr_idx(4MB uint16) = ~8 MB.
// ---------------------------------------------------------------------------
extern "C" void kernel_launch(void* const* d_in, const int* in_sizes, int n_in,
                              void* d_out, int out_size, void* d_ws, size_t ws_size,
                              hipStream_t stream) {
    const float* x    = (const float*)d_in[0];
    const float* adj  = (const float*)d_in[1];
    const float* w    = (const float*)d_in[2];
    const float* bias = (const float*)d_in[3];
    float* out = (float*)d_out;

    unsigned short* h    = (unsigned short*)d_ws;              // [N, F] bf16
    unsigned short* out2 = h + (size_t)N * F;                  // [N, F] bf16
    int* csr_cnt = (int*)(out2 + (size_t)N * F);               // [N]
    unsigned short* csr_idx = (unsigned short*)(csr_cnt + N);  // [N, CAP]

    gemm_mfma<<<N / 32, 256, 0, stream>>>(x, w, h);
    aggregate_relu_build_csr<<<N, 256, 0, stream>>>(adj, h, bias, out2, csr_idx, csr_cnt);
    neighbor_max_csr<<<N, 256, 0, stream>>>(csr_idx, csr_cnt, out2, out);
}